// Round 3
// baseline (561.571 us; speedup 1.0000x reference)
//
#include <hip/hip_runtime.h>
#include <stdint.h>

// RelativePositionEncoding: out[i,j,:] = W[idx_res] + W[66+idx_tok]
//                                      + ment*W[132] + W[133+idx_chain]
// Two-pass: (A) pack per-pair indices into u32 [n*n] in d_ws (div-free 2D
// grid); (B) grid-stride main pass, W staged in LDS (71 KB, 2 blocks/CU),
// 32 lanes/pair x 16B stores, register-prefetched index load.

typedef float f4 __attribute__((ext_vector_type(4)));

#define NCH4 32          // 128 channels / 4
#define NROWS 139
#define BLK_B 512        // kernel B block (8 waves); 2 blocks/CU (LDS-limited)
#define GRID_B 512       // 2 per CU

__global__ __launch_bounds__(256) void idx_kernel(
    const float* __restrict__ feats,  // [n,10]
    uint32_t* __restrict__ pidx,      // [n*n]
    int n)
{
    const int j = blockIdx.x * blockDim.x + threadIdx.x;
    const int i = blockIdx.y;
    if (j >= n) return;

    // i-side: block-uniform -> scalar loads
    const float res_i = feats[i * 10 + 0];
    const float tok_i = feats[i * 10 + 1];
    const float asym_i = feats[i * 10 + 2];
    const float ent_i = feats[i * 10 + 3];
    const float sym_i = feats[i * 10 + 4];

    // j-side: rows are 40B -> 8B aligned; use float2 + float
    const float2* fj2 = (const float2*)(feats + j * 10);
    const float2 rt = fj2[0];                 // res_j, tok_j
    const float2 ae = fj2[1];                 // asym_j, ent_j
    const float sym_j = feats[j * 10 + 4];

    const float dres = res_i - rt.x;
    const float dtok = tok_i - rt.y;
    const float dsym = sym_i - sym_j;
    const bool same_chain = (asym_i == ae.x);
    const bool same_res   = (dres == 0.0f);
    const uint32_t ment   = (ent_i == ae.y) ? 1u : 0u;

    // nearest-bin == clamped integer (feats are integer-valued)
    const float dr = fminf(fmaxf(dres + 32.0f, 0.0f), 64.0f);
    const uint32_t idx_res = same_chain ? (uint32_t)dr : 65u;
    const float dt = fminf(fmaxf(dtok + 32.0f, 0.0f), 64.0f);
    const uint32_t idx_tok = (same_chain && same_res) ? (uint32_t)dt : 65u;
    const float dc = fminf(fmaxf(dsym + 2.0f, 0.0f), 4.0f);
    const uint32_t idx_chain = (!same_chain) ? (uint32_t)dc : 5u;

    pidx[i * n + j] = idx_res | (idx_tok << 7) | (idx_chain << 14) | (ment << 17);
}

__global__ __launch_bounds__(BLK_B) void relpos_main(
    const uint32_t* __restrict__ pidx,  // [npairs]
    const f4* __restrict__ W4,          // [139*32]
    f4* __restrict__ out4,              // [npairs*32]
    int npairs)
{
    __shared__ f4 lw[NROWS * NCH4];     // 71168 B
    for (int t = threadIdx.x; t < NROWS * NCH4; t += BLK_B)
        lw[t] = W4[t];
    __syncthreads();

    const int c = threadIdx.x & 31;                 // float4 channel
    const int pairs_per_blk = BLK_B / 32;           // 16
    const int stride = GRID_B * pairs_per_blk;      // 8192
    int r = blockIdx.x * pairs_per_blk + (threadIdx.x >> 5);

    // loop-invariant entity row -> registers
    const f4 e = lw[132 * NCH4 + c];

    uint32_t p = (r < npairs) ? pidx[r] : 0u;
    while (r < npairs) {
        const int rn = r + stride;
        uint32_t pn = 0u;
        if (rn < npairs) pn = pidx[rn];             // prefetch next iter

        const uint32_t ir = p & 127u;
        const uint32_t it = (p >> 7) & 127u;
        const uint32_t ic = (p >> 14) & 7u;
        const float ment = (float)((p >> 17) & 1u);

        const f4 a = lw[ir * NCH4 + c];
        const f4 b = lw[(66u + it) * NCH4 + c];
        const f4 d = lw[(133u + ic) * NCH4 + c];

        out4[(long)r * NCH4 + c] = a + b + ment * e + d;

        r = rn;
        p = pn;
    }
}

extern "C" void kernel_launch(void* const* d_in, const int* in_sizes, int n_in,
                              void* d_out, int out_size, void* d_ws, size_t ws_size,
                              hipStream_t stream) {
    const float* feats = (const float*)d_in[0];
    const f4* W4       = (const f4*)d_in[1];
    f4* out4           = (f4*)d_out;
    uint32_t* pidx     = (uint32_t*)d_ws;

    const int n = in_sizes[0] / 10;   // b=1, [1,n,10]
    const int npairs = n * n;

    dim3 gA((n + 255) / 256, n);
    idx_kernel<<<gA, 256, 0, stream>>>(feats, pidx, n);

    relpos_main<<<GRID_B, BLK_B, 0, stream>>>(pidx, W4, out4, npairs);
}

// Round 4
// 504.819 us; speedup vs baseline: 1.1124x; 1.1124x over previous
//
#include <hip/hip_runtime.h>
#include <stdint.h>

// RelativePositionEncoding via combined-row table.
// The (idx_res, idx_tok, ment, idx_chain) tuple has only 270 reachable
// combinations:
//   off-chain:            idx_res=65, idx_tok=65, idx_chain in 0..4, ment  -> ids 0..9
//   same-chain, dres!=0:  idx_tok=65, idx_chain=5, idx_res  in 0..64, ment -> ids 10..139
//   same-chain, dres==0:  idx_res=32, idx_chain=5, idx_tok  in 0..64, ment -> ids 140..269
// Precompute T[270][128] = W[ir]+W[66+it]+ment*W[132]+W[133+ic] (138 KB,
// L2/L1-resident), then main pass = u16 id load + one 16B gather + NT store.
// Pure write-streaming: 512 MiB out @ ~6.3 TB/s floor.

typedef float f4 __attribute__((ext_vector_type(4)));

#define NCH4 32      // 128 channels / 4
#define NCOMBO 270

__global__ __launch_bounds__(256) void table_kernel(
    const f4* __restrict__ W4,   // [139*32]
    f4* __restrict__ T4)         // [270*32]
{
    const int t = blockIdx.x * blockDim.x + threadIdx.x;  // 270*32 = 8640
    if (t >= NCOMBO * NCH4) return;
    const int id = t >> 5;
    const int c  = t & 31;
    int ir, it, ic, m;
    if (id < 10)       { ic = id >> 1;        m = id & 1; ir = 65; it = 65; }
    else if (id < 140) { int u = id - 10;  ir = u >> 1; m = u & 1; it = 65; ic = 5; }
    else               { int u = id - 140; it = u >> 1; m = u & 1; ir = 32; ic = 5; }
    // exact reference sum order: ((a + b) + ment*e) + d
    f4 v = W4[ir * NCH4 + c] + W4[(66 + it) * NCH4 + c];
    if (m) v += W4[132 * NCH4 + c];
    v += W4[(133 + ic) * NCH4 + c];
    T4[t] = v;
}

__global__ __launch_bounds__(256) void idx_kernel(
    const float* __restrict__ feats,  // [n,10]
    uint16_t* __restrict__ ids,       // [n*n]
    int n)
{
    const int j = blockIdx.x * blockDim.x + threadIdx.x;
    const int i = blockIdx.y;
    if (j >= n) return;

    const float res_i  = feats[i * 10 + 0];
    const float tok_i  = feats[i * 10 + 1];
    const float asym_i = feats[i * 10 + 2];
    const float ent_i  = feats[i * 10 + 3];
    const float sym_i  = feats[i * 10 + 4];

    const float2* fj2 = (const float2*)(feats + j * 10);  // rows 40B -> 8B aligned
    const float2 rt = fj2[0];                  // res_j, tok_j
    const float2 ae = fj2[1];                  // asym_j, ent_j
    const float sym_j = feats[j * 10 + 4];

    const float dres = res_i - rt.x;
    const float dtok = tok_i - rt.y;
    const float dsym = sym_i - sym_j;
    const bool same_chain = (asym_i == ae.x);
    const bool same_res   = (dres == 0.0f);
    const uint32_t ment   = (ent_i == ae.y) ? 1u : 0u;

    uint32_t id;
    if (!same_chain) {
        const uint32_t ic = (uint32_t)fminf(fmaxf(dsym + 2.0f, 0.0f), 4.0f);
        id = (ic << 1) | ment;
    } else if (!same_res) {
        const uint32_t ir = (uint32_t)fminf(fmaxf(dres + 32.0f, 0.0f), 64.0f);
        id = 10u + ((ir << 1) | ment);
    } else {
        const uint32_t it = (uint32_t)fminf(fmaxf(dtok + 32.0f, 0.0f), 64.0f);
        id = 140u + ((it << 1) | ment);
    }
    ids[i * n + j] = (uint16_t)id;
}

__global__ __launch_bounds__(256) void main_kernel(
    const uint16_t* __restrict__ ids,  // [npairs]
    const f4* __restrict__ T4,         // [270*32]
    f4* __restrict__ out4,             // [npairs*32]
    long total4)
{
    const long tid = (long)blockIdx.x * 256 + threadIdx.x;
    if (tid >= total4) return;
    const long r = tid >> 5;           // pair index
    const int  c = (int)(tid & 31);    // float4 channel
    const uint32_t id = ids[r];
    const f4 v = T4[id * NCH4 + c];
    __builtin_nontemporal_store(v, &out4[tid]);
}

extern "C" void kernel_launch(void* const* d_in, const int* in_sizes, int n_in,
                              void* d_out, int out_size, void* d_ws, size_t ws_size,
                              hipStream_t stream) {
    const float* feats = (const float*)d_in[0];
    const f4* W4       = (const f4*)d_in[1];
    f4* out4           = (f4*)d_out;

    const int n = in_sizes[0] / 10;   // b=1, [1,n,10]
    const long npairs = (long)n * n;
    const long total4 = npairs * NCH4;

    // ws layout: ids [npairs u16], then T [270*128 floats], 256B-aligned
    uint16_t* ids = (uint16_t*)d_ws;
    size_t ids_bytes = ((size_t)npairs * 2 + 255) & ~(size_t)255;
    f4* T4 = (f4*)((char*)d_ws + ids_bytes);

    table_kernel<<<(NCOMBO * NCH4 + 255) / 256, 256, 0, stream>>>(W4, T4);

    dim3 gIdx((n + 255) / 256, n);
    idx_kernel<<<gIdx, 256, 0, stream>>>(feats, ids, n);

    const long gridB = (total4 + 255) / 256;
    main_kernel<<<dim3((unsigned)gridB), 256, 0, stream>>>(ids, T4, out4, total4);
}